// Round 1
// baseline (356.230 us; speedup 1.0000x reference)
//
#include <hip/hip_runtime.h>

#define B_ 8
#define N_ 262144
#define M_ 100
#define C_ 7
#define EPSF 1e-7f

// ---------------- helpers ----------------

__device__ __forceinline__ float softplus0(float x) {
  // jnp.logaddexp(0, x) = max(x,0) + log1p(exp(-|x|))
  return fmaxf(x, 0.0f) + log1pf(expf(-fabsf(x)));
}

// ---------------- kernel 1: per-image softplus sum ----------------
// grid = B*224 blocks, 256 threads; each thread 8 float4 = 32 elems.
// N*C = 1835008 floats/image = 458752 float4 = 224 blocks * 2048 float4.
__global__ void k_softplus(const float* __restrict__ cls, double* __restrict__ sp_sum) {
  const int b   = blockIdx.x / 224;
  const int blk = blockIdx.x % 224;
  const float4* p = reinterpret_cast<const float4*>(cls + (size_t)b * (size_t)(N_ * C_));
  const int base = blk * 2048 + threadIdx.x;
  float acc = 0.f;
#pragma unroll
  for (int k = 0; k < 8; ++k) {
    float4 v = p[base + k * 256];
    acc += softplus0(v.x) + softplus0(v.y) + softplus0(v.z) + softplus0(v.w);
  }
  __shared__ float red[256];
  const int t = threadIdx.x;
  red[t] = acc;
  __syncthreads();
  for (int s = 128; s > 0; s >>= 1) {
    if (t < s) red[t] += red[t + s];
    __syncthreads();
  }
  if (t == 0) atomicAdd(&sp_sum[b], (double)red[0]);
}

// ---------------- kernel 2: argmin_n dist(gt, anchor) per (b,m) ----------------
// One block per (b,m). Packed (clamped-d2-bits << 32) | anchor_idx: u64 min
// gives exact (min d2, first index) semantics matching jnp.argmin.
__global__ void k_argmin(const float* __restrict__ anchors,
                         const float* __restrict__ gt_boxes,
                         unsigned long long* __restrict__ amin) {
  const int bm = blockIdx.x;
  const float4 g = reinterpret_cast<const float4*>(gt_boxes)[bm];
  // gc = (lt + rb) * 0.5  (matches (a+b)/2 exactly: /2 == *0.5)
  const float gx = __fmul_rn(__fadd_rn(g.x, g.z), 0.5f);
  const float gy = __fmul_rn(__fadd_rn(g.y, g.w), 0.5f);
  const float t1 = __fadd_rn(__fmul_rn(gx, gx), __fmul_rn(gy, gy));
  const float2* an = reinterpret_cast<const float2*>(anchors);
  float best = __int_as_float(0x7f800000);  // +inf
  unsigned bestn = 0;
#pragma unroll 4
  for (int n = threadIdx.x; n < N_; n += 256) {
    float2 a = an[n];
    float t2  = __fadd_rn(__fmul_rn(a.x, a.x), __fmul_rn(a.y, a.y));
    float dot = __fmaf_rn(gy, a.y, __fmul_rn(gx, a.x));
    float d2  = __fsub_rn(__fadd_rn(t1, t2), __fadd_rn(dot, dot));
    d2 = fmaxf(d2, 0.0f);  // ref: sqrt(clip(d2,0)); ties at 0 -> first idx
    if (d2 < best) { best = d2; bestn = (unsigned)n; }  // strict < keeps earliest n
  }
  unsigned long long pk =
      ((unsigned long long)__float_as_uint(best) << 32) | (unsigned long long)bestn;
  __shared__ unsigned long long red[256];
  const int t = threadIdx.x;
  red[t] = pk;
  __syncthreads();
  for (int s = 128; s > 0; s >>= 1) {
    if (t < s) {
      unsigned long long o = red[t + s];
      if (o < red[t]) red[t] = o;
    }
    __syncthreads();
  }
  if (t == 0) amin[bm] = red[0];
}

// ---------------- kernel 3: per-anchor sw = pos/neg weights, summed ----------------
// grid = (N/(256*4), B); GT centers + assigned indices staged in LDS.
__global__ void k_sw(const float* __restrict__ anchors,
                     const float* __restrict__ gt_boxes,
                     const unsigned long long* __restrict__ amin,
                     double* __restrict__ sw_sum) {
  const int b = blockIdx.y;
  __shared__ float gxs[M_], gys[M_], t1s[M_];
  __shared__ unsigned asg[M_];
  if (threadIdx.x < M_) {
    float4 g = reinterpret_cast<const float4*>(gt_boxes)[b * M_ + threadIdx.x];
    float gx = __fmul_rn(__fadd_rn(g.x, g.z), 0.5f);
    float gy = __fmul_rn(__fadd_rn(g.y, g.w), 0.5f);
    gxs[threadIdx.x] = gx;
    gys[threadIdx.x] = gy;
    t1s[threadIdx.x] = __fadd_rn(__fmul_rn(gx, gx), __fmul_rn(gy, gy));
    asg[threadIdx.x] = (unsigned)(amin[b * M_ + threadIdx.x] & 0xffffffffULL);
  }
  __syncthreads();
  const float2* an = reinterpret_cast<const float2*>(anchors);
  float accsw = 0.f;
#pragma unroll
  for (int k = 0; k < 4; ++k) {
    const int n = blockIdx.x * 1024 + k * 256 + threadIdx.x;
    float2 a = an[n];
    float t2 = __fadd_rn(__fmul_rn(a.x, a.x), __fadd_rn(__fmul_rn(a.y, a.y), 0.0f));
    // (keep t2 rounding identical to kernel 2)
    t2 = __fadd_rn(__fmul_rn(a.x, a.x), __fmul_rn(a.y, a.y));
    float mind = __int_as_float(0x7f800000);
    bool pos = false;
    const unsigned un = (unsigned)n;
    for (int m = 0; m < M_; ++m) {
      float dot = __fmaf_rn(gys[m], a.y, __fmul_rn(gxs[m], a.x));
      float d2  = __fsub_rn(__fadd_rn(t1s[m], t2), __fadd_rn(dot, dot));
      mind = fminf(mind, d2);
      pos |= (asg[m] == un);
    }
    const bool neg = sqrtf(fmaxf(mind, 0.0f)) > 3.0f;
    accsw += (pos ? 2.0f : 1.0f) * (neg ? 1.0f : 0.1f);
  }
  __shared__ float red[256];
  const int t = threadIdx.x;
  red[t] = accsw;
  __syncthreads();
  for (int s = 128; s > 0; s >>= 1) {
    if (t < s) red[t] += red[t + s];
    __syncthreads();
  }
  if (t == 0) atomicAdd(&sw_sum[b], (double)red[0]);
}

// ---------------- kernel 4: per-image finalize (tgt sum, uniqueness, GIoU) ----------------
__global__ void k_final_img(const float* __restrict__ pred_cls,
                            const float* __restrict__ pred_reg,
                            const float* __restrict__ anchors,
                            const float* __restrict__ strides,
                            const float* __restrict__ gt_boxes,
                            const int* __restrict__ gt_labels,
                            const unsigned long long* __restrict__ amin,
                            const double* __restrict__ sp_sum,
                            const double* __restrict__ sw_sum,
                            float* __restrict__ lc, float* __restrict__ lb) {
  const int b = blockIdx.x;
  const int t = threadIdx.x;  // 128 threads
  __shared__ unsigned asg[M_];
  __shared__ int cid[M_];
  __shared__ unsigned srt[M_];
  __shared__ float red[128];
  __shared__ int dupCount;
  if (t == 0) dupCount = 0;
  if (t < M_) {
    asg[t] = (unsigned)(amin[b * M_ + t] & 0xffffffffULL);
    int c = gt_labels[b * M_ + t] - 1;
    c = c < 0 ? 0 : (c > C_ - 1 ? C_ - 1 : c);
    cid[t] = c;
  }
  __syncthreads();

  // tgt sum with (anchor,cls)-pair dedup (scatter-set semantics), plus
  // anchor-index duplicate detection for the uniqueness predicate.
  float tg = 0.f;
  if (t < M_) {
    bool dupPair = false, dupIdx = false;
    for (int m = 0; m < t; ++m) {
      if (asg[m] == asg[t]) {
        dupIdx = true;
        if (cid[m] == cid[t]) dupPair = true;
      }
    }
    if (!dupPair) tg = pred_cls[((size_t)b * N_ + asg[t]) * C_ + cid[t]];
    if (dupIdx) atomicAdd(&dupCount, 1);
  }
  red[t] = tg;
  __syncthreads();
  for (int s = 64; s > 0; s >>= 1) {
    if (t < s) red[t] += red[t + s];
    __syncthreads();
  }
  const float tgt_total = red[0];
  const bool uniqueAll = (dupCount == 0);  // sum(pos_mask) == M  <=>  all distinct
  __syncthreads();

  // rank sort (only valid/needed when all distinct)
  if (uniqueAll && t < M_) {
    const unsigned v = asg[t];
    int rank = 0;
    for (int m = 0; m < M_; ++m) rank += (asg[m] < v) ? 1 : 0;
    srt[rank] = v;
  }
  __syncthreads();

  float gl = 0.f;
  if (t < M_) {
    const unsigned q = uniqueAll ? srt[t] : asg[t];
    float4 r = reinterpret_cast<const float4*>(pred_reg)[(size_t)b * N_ + q];
    float2 a = reinterpret_cast<const float2*>(anchors)[q];
    float s = strides[q];
    float cx = a.x + r.x * s, cy = a.y + r.y * s;
    float hx = (expf(r.z) * s) * 0.5f, hy = (expf(r.w) * s) * 0.5f;
    float px0 = cx - hx, py0 = cy - hy, px1 = cx + hx, py1 = cy + hy;
    float4 g = reinterpret_cast<const float4*>(gt_boxes)[b * M_ + t];
    float ap = (px1 - px0) * (py1 - py0);
    float ag = (g.z - g.x) * (g.w - g.y);
    float ltx = fmaxf(px0, g.x), lty = fmaxf(py0, g.y);
    float rbx = fminf(px1, g.z), rby = fminf(py1, g.w);
    float wix = fmaxf(rbx - ltx, 0.f), wiy = fmaxf(rby - lty, 0.f);
    float inter = wix * wiy;
    float uni = ap + ag - inter;
    float iou = inter / (uni + EPSF);
    float lcx = fminf(px0, g.x), lcy = fminf(py0, g.y);
    float rcx = fmaxf(px1, g.z), rcy = fmaxf(py1, g.w);
    float wcx = fmaxf(rcx - lcx, 0.f), wcy = fmaxf(rcy - lcy, 0.f);
    float ac = wcx * wcy;
    float giou = iou - (ac - uni) / (ac + EPSF);
    gl = 1.f - giou;
  }
  __syncthreads();
  red[t] = gl;
  __syncthreads();
  for (int s = 64; s > 0; s >>= 1) {
    if (t < s) red[t] += red[t + s];
    __syncthreads();
  }
  if (t == 0) {
    lb[b] = red[0] / (float)M_;
    float bce = (float)((sp_sum[b] - (double)tgt_total) / (double)(N_ * C_));
    float swm = (float)(sw_sum[b] / (double)N_);
    lc[b] = bce * swm;
  }
}

// ---------------- kernel 5: scalar combine ----------------
__global__ void k_total(const float* __restrict__ lc, const float* __restrict__ lb,
                        float* __restrict__ out) {
  if (threadIdx.x == 0 && blockIdx.x == 0) {
    float sc = 0.f, sb = 0.f;
    for (int b = 0; b < B_; ++b) { sc += lc[b]; sb += lb[b]; }
    out[0] = sc / 8.0f + 2.0f * (sb / 8.0f);
  }
}

// ---------------- launch ----------------
extern "C" void kernel_launch(void* const* d_in, const int* in_sizes, int n_in,
                              void* d_out, int out_size, void* d_ws, size_t ws_size,
                              hipStream_t stream) {
  (void)in_sizes; (void)n_in; (void)out_size; (void)ws_size;
  const float* pred_cls = (const float*)d_in[0];
  const float* pred_reg = (const float*)d_in[1];
  const float* anchors  = (const float*)d_in[2];
  const float* strides  = (const float*)d_in[3];
  const float* gt_boxes = (const float*)d_in[4];
  const int*   gt_labels = (const int*)d_in[5];
  float* out = (float*)d_out;

  char* ws = (char*)d_ws;
  double* sp_sum = (double*)(ws);          // 8 doubles
  double* sw_sum = (double*)(ws + 64);     // 8 doubles
  unsigned long long* amin = (unsigned long long*)(ws + 128);  // 800 u64
  float* lc = (float*)(ws + 128 + 6400);   // 8 floats
  float* lb = (float*)(ws + 128 + 6400 + 32);  // 8 floats

  hipMemsetAsync(d_ws, 0, 128, stream);  // zero the two accumulator arrays

  k_softplus<<<dim3(B_ * 224), dim3(256), 0, stream>>>(pred_cls, sp_sum);
  k_argmin<<<dim3(B_ * M_), dim3(256), 0, stream>>>(anchors, gt_boxes, amin);
  k_sw<<<dim3(N_ / 1024, B_), dim3(256), 0, stream>>>(anchors, gt_boxes, amin, sw_sum);
  k_final_img<<<dim3(B_), dim3(128), 0, stream>>>(pred_cls, pred_reg, anchors, strides,
                                                  gt_boxes, gt_labels, amin, sp_sum,
                                                  sw_sum, lc, lb);
  k_total<<<dim3(1), dim3(64), 0, stream>>>(lc, lb, out);
}